// Round 5
// baseline (117.353 us; speedup 1.0000x reference)
//
#include <hip/hip_runtime.h>
#include <math.h>

// riemannian_exp: out[b] = key_poses[argmax(ybin[b])] @ Rodrigues(yres[b])
// B = 1048576, C = 100.
// This round: flat-coalesced tile staging. Each block owns 64 rows (25.6 KB of
// ybin). The tile is loaded with perfectly contiguous per-instruction addresses
// (lane i <- chunk i: one aligned 1KB segment per wave-instr), staged to LDS,
// then argmax'd by 4-lane groups via conflict-free ds_read_b128 (row stride =
// 25 chunks, odd -> even bank-slot spread).

typedef float fvec4 __attribute__((ext_vector_type(4)));

#define TILE_ROWS   64
#define TILE_CHUNKS 1600   // 64 rows * 25 float4 chunks

__global__ __launch_bounds__(256) void rexp_flat_kernel(
    const float* __restrict__ ybin,      // [B, 100]
    const float* __restrict__ yres,      // [B, 3]
    const float* __restrict__ key_poses, // [100, 3, 3]
    float* __restrict__ out)             // [B, 3, 3]
{
    __shared__ fvec4 s_ybin[TILE_CHUNKS];  // 25.6 KB
    __shared__ float s_kp[900];
    __shared__ float s_yres[192];          // 64 rows * 3
    __shared__ float s_out[576];           // 64 rows * 9

    const int tid = threadIdx.x;
    const long long tile = blockIdx.x;
    const long long row0 = tile * TILE_ROWS;

    // stage key_poses (L2-resident, 3.6 KB) and yres (768 B) coalesced
    for (int i = tid; i < 900; i += 256) s_kp[i] = key_poses[i];
    if (tid < 48)
        reinterpret_cast<fvec4*>(s_yres)[tid] =
            reinterpret_cast<const fvec4*>(yres + row0 * 3)[tid];

    // ---- flat-coalesced load of the 25.6 KB tile into registers ----
    const fvec4* g = reinterpret_cast<const fvec4*>(ybin + row0 * 100);
    fvec4 v[7];
    #pragma unroll
    for (int r = 0; r < 7; ++r) {
        int c = r * 256 + tid;
        if (c < TILE_CHUNKS) v[r] = g[c];     // consecutive lanes -> consecutive 16B
    }
    // ---- spill to LDS (linear; conflict-free: slot = tid mod 8) ----
    #pragma unroll
    for (int r = 0; r < 7; ++r) {
        int c = r * 256 + tid;
        if (c < TILE_CHUNKS) s_ybin[c] = v[r];
    }
    __syncthreads();

    // ---- cooperative argmax from LDS: 4 lanes per row ----
    const int lane4 = tid & 3;
    const int rloc  = tid >> 2;               // 0..63
    const fvec4* rb = &s_ybin[rloc * 25];
    float best = -INFINITY;
    int bi = 0;
    #pragma unroll
    for (int j = 0; j < 7; ++j) {
        int c = lane4 + j * 4;
        if (c < 25) {
            fvec4 x = rb[c];
            int i0 = c * 4;
            if (x.x > best) { best = x.x; bi = i0;     }
            if (x.y > best) { best = x.y; bi = i0 + 1; }
            if (x.z > best) { best = x.z; bi = i0 + 2; }
            if (x.w > best) { best = x.w; bi = i0 + 3; }
        }
    }
    #pragma unroll
    for (int m = 1; m <= 2; m <<= 1) {
        float ob = __shfl_xor(best, m);
        int   oi = __shfl_xor(bi, m);
        if (ob > best || (ob == best && oi < bi)) { best = ob; bi = oi; }
    }

    // ---- Rodrigues + matmul on group leader lanes ----
    if (lane4 == 0) {
        float rx = s_yres[rloc * 3 + 0];
        float ry = s_yres[rloc * 3 + 1];
        float rz = s_yres[rloc * 3 + 2];
        float angle = sqrtf(rx * rx + ry * ry + rz * rz);
        float inv = 1.0f / fmaxf(angle, 1e-12f);
        float ax = rx * inv, ay = ry * inv, az = rz * inv;
        float s, cosv;
        __sincosf(angle, &s, &cosv);
        float c = 1.0f - cosv;

        float axx = ax * ax, ayy = ay * ay, azz = az * az;
        float axy = ax * ay, axz = ax * az, ayz = ay * az;

        float R00 = 1.0f + c * (-ayy - azz);
        float R01 = -s * az + c * axy;
        float R02 =  s * ay + c * axz;
        float R10 =  s * az + c * axy;
        float R11 = 1.0f + c * (-axx - azz);
        float R12 = -s * ax + c * ayz;
        float R20 = -s * ay + c * axz;
        float R21 =  s * ax + c * ayz;
        float R22 = 1.0f + c * (-axx - ayy);

        const float* P = &s_kp[bi * 9];
        float P00 = P[0], P01 = P[1], P02 = P[2];
        float P10 = P[3], P11 = P[4], P12 = P[5];
        float P20 = P[6], P21 = P[7], P22 = P[8];

        float* o = &s_out[rloc * 9];
        o[0] = P00 * R00 + P01 * R10 + P02 * R20;
        o[1] = P00 * R01 + P01 * R11 + P02 * R21;
        o[2] = P00 * R02 + P01 * R12 + P02 * R22;
        o[3] = P10 * R00 + P11 * R10 + P12 * R20;
        o[4] = P10 * R01 + P11 * R11 + P12 * R21;
        o[5] = P10 * R02 + P11 * R12 + P12 * R22;
        o[6] = P20 * R00 + P21 * R10 + P22 * R20;
        o[7] = P20 * R01 + P21 * R11 + P22 * R21;
        o[8] = P20 * R02 + P21 * R12 + P22 * R22;
    }
    __syncthreads();

    // ---- coalesced store: 576 floats = 144 float4 ----
    if (tid < 144)
        reinterpret_cast<fvec4*>(out + row0 * 9)[tid] =
            reinterpret_cast<const fvec4*>(s_out)[tid];
}

// ---------------- Fallback: fused single kernel (generic) ----------------
__global__ void rexp_generic_kernel(
    const float* __restrict__ ybin, const float* __restrict__ yres,
    const float* __restrict__ key_poses, float* __restrict__ out,
    int B, int C)
{
    long long b = (long long)blockIdx.x * blockDim.x + threadIdx.x;
    if (b >= B) return;
    const float* row = ybin + b * C;
    float best = -INFINITY; int bi = 0;
    for (int j = 0; j < C; ++j) if (row[j] > best) { best = row[j]; bi = j; }
    float rx = yres[b*3], ry = yres[b*3+1], rz = yres[b*3+2];
    float angle = sqrtf(rx*rx + ry*ry + rz*rz);
    float inv = 1.0f / fmaxf(angle, 1e-12f);
    float ax = rx*inv, ay = ry*inv, az = rz*inv;
    float s, cosv; __sincosf(angle, &s, &cosv);
    float c = 1.0f - cosv;
    float axx=ax*ax, ayy=ay*ay, azz=az*az, axy=ax*ay, axz=ax*az, ayz=ay*az;
    float R00=1.0f+c*(-ayy-azz), R01=-s*az+c*axy, R02= s*ay+c*axz;
    float R10= s*az+c*axy, R11=1.0f+c*(-axx-azz), R12=-s*ax+c*ayz;
    float R20=-s*ay+c*axz, R21= s*ax+c*ayz, R22=1.0f+c*(-axx-ayy);
    const float* P = key_poses + bi * 9;
    float* o = out + b * 9;
    o[0]=P[0]*R00+P[1]*R10+P[2]*R20; o[1]=P[0]*R01+P[1]*R11+P[2]*R21; o[2]=P[0]*R02+P[1]*R12+P[2]*R22;
    o[3]=P[3]*R00+P[4]*R10+P[5]*R20; o[4]=P[3]*R01+P[4]*R11+P[5]*R21; o[5]=P[3]*R02+P[4]*R12+P[5]*R22;
    o[6]=P[6]*R00+P[7]*R10+P[8]*R20; o[7]=P[6]*R01+P[7]*R11+P[8]*R21; o[8]=P[6]*R02+P[7]*R12+P[8]*R22;
}

extern "C" void kernel_launch(void* const* d_in, const int* in_sizes, int n_in,
                              void* d_out, int out_size, void* d_ws, size_t ws_size,
                              hipStream_t stream) {
    const float* ybin      = (const float*)d_in[0];
    const float* yres      = (const float*)d_in[1];
    const float* key_poses = (const float*)d_in[2];
    float* out = (float*)d_out;

    int B = in_sizes[1] / 3;
    int C = in_sizes[0] / B;   // == 100 here

    if (C == 100 && (B % TILE_ROWS) == 0) {
        int grid = B / TILE_ROWS;   // 16384 blocks of 256 threads
        rexp_flat_kernel<<<grid, 256, 0, stream>>>(ybin, yres, key_poses, out);
    } else {
        rexp_generic_kernel<<<(B + 255) / 256, 256, 0, stream>>>(
            ybin, yres, key_poses, out, B, C);
    }
}